// Round 1
// baseline (6213.027 us; speedup 1.0000x reference)
//
#include <hip/hip_runtime.h>
#include <hip/hip_bf16.h>

#define HID   256
#define BATCH 2048
#define NGATE 1024
#define NWG   64
#define BM    32      // batch rows per workgroup
#define TPB   512     // 8 waves

typedef __attribute__((ext_vector_type(8))) short bf16x8;
typedef __attribute__((ext_vector_type(4))) float f32x4;

__device__ __forceinline__ unsigned short f2bf(float x){
  unsigned int u = __builtin_bit_cast(unsigned int, x);
  u += 0x7fffu + ((u >> 16) & 1u);          // RNE
  return (unsigned short)(u >> 16);
}

__device__ __forceinline__ float fsigm(float x){
  return __builtin_amdgcn_rcpf(1.0f + __expf(-x));
}
__device__ __forceinline__ float ftanh_(float x){
  return fmaf(2.0f, __builtin_amdgcn_rcpf(1.0f + __expf(-2.0f*x)), -1.0f);
}

// Pack W_ih and (W_ih+W_hh) into MFMA B-fragment order:
// frag(nt,kt) is 1024B, lane-linear: lane l holds W[nt*16 + (l&15)][kt*32 + (l>>4)*8 + j]
__global__ void pack_kernel(const float* __restrict__ Wih, const float* __restrict__ Whh,
                            const float* __restrict__ bih, const float* __restrict__ bhh,
                            unsigned short* __restrict__ Wih_p,
                            unsigned short* __restrict__ Wsum_p,
                            float* __restrict__ bias){
  int tid = blockIdx.x * blockDim.x + threadIdx.x;   // 0..262143
  int j  = tid & 7;
  int ln = (tid >> 3) & 63;
  int kt = (tid >> 9) & 7;
  int nt = tid >> 12;
  int n = nt*16 + (ln & 15);
  int k = kt*32 + (ln >> 4)*8 + j;
  float wih = Wih[n*HID + k];
  float whh = Whh[n*HID + k];
  Wih_p[tid]  = f2bf(wih);
  Wsum_p[tid] = f2bf(wih + whh);
  if (tid < NGATE) bias[tid] = bih[tid] + bhh[tid];
}

// Persistent per-batch-slice LSTM. WG g owns rows [32g, 32g+32). Wave w owns
// hidden units [32w, 32w+32) (all 4 gates for those units), so after the
// elementwise update it writes exactly A-frag k-tile w for the next step.
__global__ __launch_bounds__(TPB, 2)
void lstm_kernel(const float* __restrict__ h_in,
                 const unsigned short* __restrict__ Wih_p,
                 const unsigned short* __restrict__ Wsum_p,
                 const float* __restrict__ bias,
                 const int* __restrict__ seqlen,
                 float* __restrict__ out){
  const int T   = seqlen[0];
  const int g   = blockIdx.x;
  const int tid = threadIdx.x;
  const int w   = tid >> 6;     // wave 0..7
  const int l   = tid & 63;
  const int l15 = l & 15;
  const int lq  = l >> 4;

  // h in A-frag packed order: frag(kt,mt) at ushort offset (kt*2+mt)*512,
  // within-frag: lane_a*8 + j where lane_a = kgroup*16 + row15. Double-buffered.
  __shared__ __align__(16) unsigned short hbuf[2][8192];   // 2 x 16 KB

  // bias for my columns: n = ga*256 + w*32 + ut*16 + l15
  float bv[4][2];
  #pragma unroll
  for (int ga = 0; ga < 4; ++ga)
    #pragma unroll
    for (int ut = 0; ut < 2; ++ut)
      bv[ga][ut] = bias[ga*256 + w*32 + ut*16 + l15];

  // Stage t=0 input x (= h_in) into hbuf[0] in A-frag layout (bf16).
  #pragma unroll
  for (int ut = 0; ut < 2; ++ut){
    const int u  = w*32 + ut*16 + l15;      // u>>5 == w
    const int kg = (u & 31) >> 3;
    const int uj = u & 7;
    #pragma unroll
    for (int mt = 0; mt < 2; ++mt){
      #pragma unroll
      for (int r = 0; r < 4; ++r){
        const int m = mt*16 + lq*4 + r;
        hbuf[0][(w*2 + mt)*512 + (kg*16 + (m & 15))*8 + uj] =
            f2bf(h_in[(size_t)(g*BM + m)*HID + u]);
      }
    }
  }

  // cell state in registers: [ut][mt][r], (row m = mt*16+lq*4+r, unit u = w*32+ut*16+l15)
  float cs[2][2][4];
  #pragma unroll
  for (int ut = 0; ut < 2; ++ut)
    #pragma unroll
    for (int mt = 0; mt < 2; ++mt)
      #pragma unroll
      for (int r = 0; r < 4; ++r)
        cs[ut][mt][r] = 0.0f;

  __syncthreads();

  int buf = 0;
  for (int t = 0; t < T; ++t){
    const unsigned short* __restrict__ Wp = (t == 0) ? Wih_p : Wsum_p;

    f32x4 acc[4][2][2];      // [gate][ut][mt]
    const f32x4 z = {0.f, 0.f, 0.f, 0.f};
    #pragma unroll
    for (int ga = 0; ga < 4; ++ga)
      #pragma unroll
      for (int ut = 0; ut < 2; ++ut){
        acc[ga][ut][0] = z; acc[ga][ut][1] = z;
      }

    // gates[m, n] = sum_k h[m,k] * W[n,k];  K=256 as 8 k-tiles of 32
    #pragma unroll
    for (int kt = 0; kt < 8; ++kt){
      bf16x8 a0 = *(const bf16x8*)&hbuf[buf][(kt*2 + 0)*512 + l*8];
      bf16x8 a1 = *(const bf16x8*)&hbuf[buf][(kt*2 + 1)*512 + l*8];
      #pragma unroll
      for (int ga = 0; ga < 4; ++ga){
        #pragma unroll
        for (int ut = 0; ut < 2; ++ut){
          const int nt = ga*16 + w*2 + ut;
          bf16x8 bfg = *(const bf16x8*)(Wp + ((size_t)(nt*8 + kt)*512 + l*8));
          acc[ga][ut][0] = __builtin_amdgcn_mfma_f32_16x16x32_bf16(a0, bfg, acc[ga][ut][0], 0, 0, 0);
          acc[ga][ut][1] = __builtin_amdgcn_mfma_f32_16x16x32_bf16(a1, bfg, acc[ga][ut][1], 0, 0, 0);
        }
      }
    }

    const int nb   = buf ^ 1;
    const int orow = (t == 0) ? 0 : (T - t);   // x_hat[0]=h_0, x_hat[T-t]=h_t
    float* __restrict__ orow_p = out + (size_t)orow * (BATCH*HID);
    const bool last = (t == T - 1);

    #pragma unroll
    for (int ut = 0; ut < 2; ++ut){
      const int u  = w*32 + ut*16 + l15;
      const int kg = (u & 31) >> 3;
      const int uj = u & 7;
      #pragma unroll
      for (int mt = 0; mt < 2; ++mt){
        #pragma unroll
        for (int r = 0; r < 4; ++r){
          const int m = mt*16 + lq*4 + r;
          const float iv = fsigm (acc[0][ut][mt][r] + bv[0][ut]);
          const float fv = fsigm (acc[1][ut][mt][r] + bv[1][ut]);
          const float gv = ftanh_(acc[2][ut][mt][r] + bv[2][ut]);
          const float ov = fsigm (acc[3][ut][mt][r] + bv[3][ut]);
          const float cn = fv * cs[ut][mt][r] + iv * gv;
          cs[ut][mt][r] = cn;
          const float hv = ov * ftanh_(cn);
          // next step's A-frag (bf16)
          hbuf[nb][(w*2 + mt)*512 + (kg*16 + (m & 15))*8 + uj] = f2bf(hv);
          // x_hat output (f32)
          const size_t gi = (size_t)(g*BM + m)*HID + u;
          orow_p[gi] = hv;
          if (last){
            out[(size_t)T*(BATCH*HID) + gi]         = hv;   // hf
            out[(size_t)(T + 1)*(BATCH*HID) + gi]   = cn;   // cf
          }
        }
      }
    }
    __syncthreads();
    buf = nb;
  }
}

extern "C" void kernel_launch(void* const* d_in, const int* in_sizes, int n_in,
                              void* d_out, int out_size, void* d_ws, size_t ws_size,
                              hipStream_t stream) {
  const float* h_in = (const float*)d_in[0];
  const float* Wih  = (const float*)d_in[1];
  const float* Whh  = (const float*)d_in[2];
  const float* bih  = (const float*)d_in[3];
  const float* bhh  = (const float*)d_in[4];
  const int*   seq  = (const int*)  d_in[5];
  float* out = (float*)d_out;

  unsigned short* Wih_p  = (unsigned short*)d_ws;          // 512 KB
  unsigned short* Wsum_p = Wih_p + (size_t)NGATE * HID;    // 512 KB
  float*          bias   = (float*)(Wsum_p + (size_t)NGATE * HID);  // 4 KB

  pack_kernel<<<dim3((NGATE*HID)/256), dim3(256), 0, stream>>>(
      Wih, Whh, bih, bhh, Wih_p, Wsum_p, bias);

  lstm_kernel<<<dim3(NWG), dim3(TPB), 0, stream>>>(
      h_in, Wih_p, Wsum_p, bias, seq, out);
}